// Round 1
// baseline (100.274 us; speedup 1.0000x reference)
//
#include <hip/hip_runtime.h>

#define N_QUBITS 16
#define N_LAYERS 4
#define N_ACTIONS 6
#define BATCH 512
#define WQ 7            // light-cone window size: i-3..i+3 (exact; see analysis)

// Complex 2x2 gate applied to the pair of amplitudes differing in window-bit j.
// State distribution: lane l holds amplitude indices n0=2l (regs ar0/ai0) and
// n1=2l+1 (ar1/ai1). Bit 0 of the 7-bit amp index is the r in-lane bit; bits
// 1..6 live in the lane index, so those gates are a shfl_xor exchange.

__global__ __launch_bounds__(256)
void qlightcone_kernel(const float* __restrict__ x,     // [BATCH, 16]
                       const float* __restrict__ wt,    // [4, 16, 3]
                       float* __restrict__ z)           // [BATCH, 16] out
{
    const int lane = threadIdx.x & 63;
    const int wave = (blockIdx.x * blockDim.x + threadIdx.x) >> 6;  // 0..8191
    const int b  = wave >> 4;       // sample
    const int qi = wave & 15;       // measured qubit
    int s = qi - 3;
    s = s < 0 ? 0 : (s > N_QUBITS - WQ ? N_QUBITS - WQ : s);  // window start, 0..9
    const int jm = qi - s;          // measured bit inside window

    // state registers: amp[2*lane + r], r in {0,1}
    float ar0 = (lane == 0) ? 1.0f : 0.0f, ai0 = 0.0f;
    float ar1 = 0.0f, ai1 = 0.0f;

    const int n0 = lane << 1, n1 = n0 | 1;
    // CZ chain sign: -1 iff odd # of adjacent (bit j, bit j+1) 1-pairs, cuts j=0..5
    const float czs0 = (__popc((n0 & (n0 >> 1)) & 0x3F) & 1) ? -1.0f : 1.0f;
    const float czs1 = (__popc((n1 & (n1 >> 1)) & 0x3F) & 1) ? -1.0f : 1.0f;

    auto apply = [&](int j,
                     float u00r, float u00i, float u01r, float u01i,
                     float u10r, float u10i, float u11r, float u11i) {
        if (j == 0) {
            // in-lane pair (n0, n1)
            float nr0 = u00r*ar0 - u00i*ai0 + u01r*ar1 - u01i*ai1;
            float ni0 = u00r*ai0 + u00i*ar0 + u01r*ai1 + u01i*ar1;
            float nr1 = u10r*ar0 - u10i*ai0 + u11r*ar1 - u11i*ai1;
            float ni1 = u10r*ai0 + u10i*ar0 + u11r*ai1 + u11i*ar1;
            ar0 = nr0; ai0 = ni0; ar1 = nr1; ai1 = ni1;
        } else {
            const int m = 1 << (j - 1);
            const bool hi = (lane & m) != 0;
            {
                float orr = __shfl_xor(ar0, m, 64);
                float oii = __shfl_xor(ai0, m, 64);
                float Ar = hi ? orr : ar0, Ai = hi ? oii : ai0;   // bit_j = 0 amp
                float Br = hi ? ar0 : orr, Bi = hi ? ai0 : oii;   // bit_j = 1 amp
                float c0r = hi ? u10r : u00r, c0i = hi ? u10i : u00i;
                float c1r = hi ? u11r : u01r, c1i = hi ? u11i : u01i;
                ar0 = c0r*Ar - c0i*Ai + c1r*Br - c1i*Bi;
                ai0 = c0r*Ai + c0i*Ar + c1r*Bi + c1i*Br;
            }
            {
                float orr = __shfl_xor(ar1, m, 64);
                float oii = __shfl_xor(ai1, m, 64);
                float Ar = hi ? orr : ar1, Ai = hi ? oii : ai1;
                float Br = hi ? ar1 : orr, Bi = hi ? ai1 : oii;
                float c0r = hi ? u10r : u00r, c0i = hi ? u10i : u00i;
                float c1r = hi ? u11r : u01r, c1i = hi ? u11i : u01i;
                ar1 = c0r*Ar - c0i*Ai + c1r*Br - c1i*Bi;
                ai1 = c0r*Ai + c0i*Ar + c1r*Bi + c1i*Br;
            }
        }
    };

    // AngleEmbedding: RY(x[b, s+j]) on window wire j (real matrix)
#pragma unroll
    for (int j = 0; j < WQ; ++j) {
        float th = x[b * N_QUBITS + s + j];
        float sn, c;
        sincosf(0.5f * th, &sn, &c);
        apply(j, c, 0.f, -sn, 0.f, sn, 0.f, c, 0.f);
    }

    // Layers: Rot per wire (shared weights), then CZ chain
    for (int l = 0; l < N_LAYERS; ++l) {
#pragma unroll
        for (int j = 0; j < WQ; ++j) {
            const int base = ((l * N_QUBITS) + (s + j)) * 3;
            float phi = wt[base + 0], th = wt[base + 1], om = wt[base + 2];
            float sn, c, ssum, csum, sdif, cdif;
            sincosf(0.5f * th, &sn, &c);
            sincosf(0.5f * (phi + om), &ssum, &csum);   // ep = csum - i*ssum
            sincosf(0.5f * (phi - om), &sdif, &cdif);   // em = cdif - i*sdif
            // m00 = ep*c; m01 = -conj(em)*s; m10 = em*s; m11 = conj(ep)*c
            apply(j,
                  csum * c, -ssum * c,
                 -cdif * sn, -sdif * sn,
                  cdif * sn, -sdif * sn,
                  csum * c,  ssum * c);
        }
        // CZ chain (diagonal): per-amp precomputed sign
        ar0 *= czs0; ai0 *= czs0;
        ar1 *= czs1; ai1 *= czs1;
    }

    // <Z_jm> = sum over amps of (1 - 2*bit_jm) * |amp|^2
    const float sm0 = ((n0 >> jm) & 1) ? -1.0f : 1.0f;
    const float sm1 = ((n1 >> jm) & 1) ? -1.0f : 1.0f;
    float p = sm0 * (ar0 * ar0 + ai0 * ai0) + sm1 * (ar1 * ar1 + ai1 * ai1);
#pragma unroll
    for (int off = 32; off > 0; off >>= 1)
        p += __shfl_xor(p, off, 64);

    if (lane == 0)
        z[b * N_QUBITS + qi] = p;
}

__global__ __launch_bounds__(256)
void fc_kernel(const float* __restrict__ z,     // [BATCH,16]
               const float* __restrict__ fw,    // [6,16]
               const float* __restrict__ fb,    // [6]
               float* __restrict__ out)         // [BATCH,6]
{
    int t = blockIdx.x * blockDim.x + threadIdx.x;
    if (t >= BATCH * N_ACTIONS) return;
    int b = t / N_ACTIONS, a = t - b * N_ACTIONS;
    float acc = fb[a];
#pragma unroll
    for (int i = 0; i < N_QUBITS; ++i)
        acc += z[b * N_QUBITS + i] * fw[a * N_QUBITS + i];
    out[t] = acc;
}

extern "C" void kernel_launch(void* const* d_in, const int* in_sizes, int n_in,
                              void* d_out, int out_size, void* d_ws, size_t ws_size,
                              hipStream_t stream) {
    const float* x    = (const float*)d_in[0];   // [512,16]
    const float* wts  = (const float*)d_in[1];   // [4,16,3]
    const float* fc_w = (const float*)d_in[2];   // [6,16]
    const float* fc_b = (const float*)d_in[3];   // [6]
    float* out = (float*)d_out;                  // [512,6]
    float* z   = (float*)d_ws;                   // [512,16] scratch

    // 512 samples x 16 outputs = 8192 waves; 4 waves / 256-thread block
    const int nblocks = (BATCH * N_QUBITS) / 4;  // 2048
    qlightcone_kernel<<<nblocks, 256, 0, stream>>>(x, wts, z);

    const int fct = BATCH * N_ACTIONS;           // 3072
    fc_kernel<<<(fct + 255) / 256, 256, 0, stream>>>(z, fc_w, fc_b, out);
}

// Round 2
// 68.141 us; speedup vs baseline: 1.4716x; 1.4716x over previous
//
#include <hip/hip_runtime.h>

#define N_QUBITS 16
#define N_LAYERS 4
#define N_ACTIONS 6
#define BATCH 512

// One block = one sample. 16 waves, wave qi computes <Z_qi> via an exact
// 7-qubit light-cone window [s, s+6], s = clamp(qi-3, 0, 9).
//
// Transformed circuit (exact algebra): per wire,
//   A1 = RY(th1) RZ(phi1) RY(x),  then per layer l>=2: A_l = RY(th_l) RZ(om_{l-1}+phi_l)
// with CZ chains between layers; trailing RZ(om4) and final CZ layer are
// diagonal -> dropped (|amp|^2 invariant). Light cone on the transformed
// circuit: A_l acts only on wires |w - qi| <= 4-l  ->  7+5+3+1 = 16 gates/wave.
//
// State: 128 amps/wave; lane holds n0=2*lane (ar0,ai0) and n1=2*lane+1 (ar1,ai1).
// Window bit 0 is in-lane; bits 1..6 map to lane bits 0..5 (shfl_xor partner).

__global__ __launch_bounds__(1024, 4)
void qdqn_fused_kernel(const float* __restrict__ x,     // [512,16]
                       const float* __restrict__ wt,    // [4,16,3]
                       const float* __restrict__ fw,    // [6,16]
                       const float* __restrict__ fb,    // [6]
                       float* __restrict__ out)         // [512,6]
{
    __shared__ float4 mats[4][N_QUBITS][2];  // [layer][wire][row-pair]: (m00,m01),(m10,m11)
    __shared__ float zsh[N_QUBITS];

    const int tid = threadIdx.x;
    const int b   = blockIdx.x;

    // ---- Phase A: 64 threads build all gate matrices into LDS ----
    if (tid < 64) {
        const int w = tid & 15;
        const int g = tid >> 4;          // g=0 -> A1 (x-dep); g=1..3 -> layer g+1
        float4 M0, M1;
        if (g == 0) {
            const float phi = wt[(0 * N_QUBITS + w) * 3 + 0];
            const float th  = wt[(0 * N_QUBITS + w) * 3 + 1];
            float sp, cp, st, ct;
            sincosf(0.5f * phi, &sp, &cp);
            sincosf(0.5f * th,  &st, &ct);
            // W1 = RY(th)*RZ(phi)
            const float w00r =  ct * cp, w00i = -ct * sp;
            const float w01r = -st * cp, w01i = -st * sp;
            const float w10r =  st * cp, w10i = -st * sp;
            const float w11r =  ct * cp, w11i =  ct * sp;
            float sx, cx;
            sincosf(0.5f * x[b * N_QUBITS + w], &sx, &cx);
            // A1 = W1 * RY(x)   (RY(x) real)
            M0.x =  w00r * cx + w01r * sx;  M0.y =  w00i * cx + w01i * sx;
            M0.z = -w00r * sx + w01r * cx;  M0.w = -w00i * sx + w01i * cx;
            M1.x =  w10r * cx + w11r * sx;  M1.y =  w10i * cx + w11i * sx;
            M1.z = -w10r * sx + w11r * cx;  M1.w = -w10i * sx + w11i * cx;
        } else {
            const float al = wt[((g - 1) * N_QUBITS + w) * 3 + 2]
                           + wt[(g * N_QUBITS + w) * 3 + 0];   // om_{l-1} + phi_l
            const float th = wt[(g * N_QUBITS + w) * 3 + 1];
            float sa, ca, st, ct;
            sincosf(0.5f * al, &sa, &ca);
            sincosf(0.5f * th, &st, &ct);
            // A = RY(th)*RZ(al)
            M0 = make_float4( ct * ca, -ct * sa, -st * ca, -st * sa);
            M1 = make_float4( st * ca, -st * sa,  ct * ca,  ct * sa);
        }
        mats[g][w][0] = M0;
        mats[g][w][1] = M1;
    }
    __syncthreads();

    // ---- Phase B: each wave simulates its light-cone window ----
    const int lane = tid & 63;
    const int qi   = tid >> 6;                       // 0..15
    int s = qi - 3;
    s = s < 0 ? 0 : (s > N_QUBITS - 7 ? N_QUBITS - 7 : s);
    const int jm = qi - s;                           // measured bit in window

    float ar0 = (lane == 0) ? 1.0f : 0.0f, ai0 = 0.0f;
    float ar1 = 0.0f, ai1 = 0.0f;

    const int n0 = lane << 1, n1 = n0 | 1;
    const float czs0 = (__popc((n0 & (n0 >> 1)) & 0x3F) & 1) ? -1.0f : 1.0f;
    const float czs1 = (__popc((n1 & (n1 >> 1)) & 0x3F) & 1) ? -1.0f : 1.0f;

    auto applyM = [&](int j, float4 m0, float4 m1) {
        if (j == 0) {
            const float nr0 = m0.x*ar0 - m0.y*ai0 + m0.z*ar1 - m0.w*ai1;
            const float ni0 = m0.x*ai0 + m0.y*ar0 + m0.z*ai1 + m0.w*ar1;
            const float nr1 = m1.x*ar0 - m1.y*ai0 + m1.z*ar1 - m1.w*ai1;
            const float ni1 = m1.x*ai0 + m1.y*ar0 + m1.z*ai1 + m1.w*ar1;
            ar0 = nr0; ai0 = ni0; ar1 = nr1; ai1 = ni1;
        } else {
            const int  m  = 1 << (j - 1);
            const bool hi = (lane & m) != 0;
            const float dr = hi ? m1.z : m0.x;   // diag coef
            const float di = hi ? m1.w : m0.y;
            const float og = hi ? m1.x : m0.z;   // off-diag coef
            const float oi = hi ? m1.y : m0.w;
            {
                const float pr = __shfl_xor(ar0, m, 64);
                const float pi = __shfl_xor(ai0, m, 64);
                const float nr = dr*ar0 - di*ai0 + og*pr - oi*pi;
                const float ni = dr*ai0 + di*ar0 + og*pi + oi*pr;
                ar0 = nr; ai0 = ni;
            }
            {
                const float pr = __shfl_xor(ar1, m, 64);
                const float pi = __shfl_xor(ai1, m, 64);
                const float nr = dr*ar1 - di*ai1 + og*pr - oi*pi;
                const float ni = dr*ai1 + di*ar1 + og*pi + oi*pr;
                ar1 = nr; ai1 = ni;
            }
        }
    };

#pragma unroll
    for (int l = 0; l < 4; ++l) {
        const int rad = 3 - l;
#pragma unroll
        for (int dj = -3; dj <= 3; ++dj) {
            if (dj < -rad || dj > rad) continue;       // folds at compile time
            const int j = jm + dj;
            if (j >= 0 && j <= 6) {                    // wave-uniform guard
                const int w = s + j;                   // = qi + dj, in [0,15]
                applyM(j, mats[l][w][0], mats[l][w][1]);
            }
        }
        if (l < 3) { ar0 *= czs0; ai0 *= czs0; ar1 *= czs1; ai1 *= czs1; }
    }

    // <Z_jm> reduction
    const float sm0 = ((n0 >> jm) & 1) ? -1.0f : 1.0f;
    const float sm1 = ((n1 >> jm) & 1) ? -1.0f : 1.0f;
    float p = sm0 * (ar0*ar0 + ai0*ai0) + sm1 * (ar1*ar1 + ai1*ai1);
#pragma unroll
    for (int off = 32; off > 0; off >>= 1)
        p += __shfl_xor(p, off, 64);
    if (lane == 0) zsh[qi] = p;
    __syncthreads();

    // ---- Phase C: FC epilogue ----
    if (tid < N_ACTIONS) {
        float acc = fb[tid];
#pragma unroll
        for (int i = 0; i < N_QUBITS; ++i)
            acc += zsh[i] * fw[tid * N_QUBITS + i];
        out[b * N_ACTIONS + tid] = acc;
    }
}

extern "C" void kernel_launch(void* const* d_in, const int* in_sizes, int n_in,
                              void* d_out, int out_size, void* d_ws, size_t ws_size,
                              hipStream_t stream) {
    const float* x    = (const float*)d_in[0];   // [512,16]
    const float* wts  = (const float*)d_in[1];   // [4,16,3]
    const float* fc_w = (const float*)d_in[2];   // [6,16]
    const float* fc_b = (const float*)d_in[3];   // [6]
    float* out = (float*)d_out;                  // [512,6]

    qdqn_fused_kernel<<<BATCH, 1024, 0, stream>>>(x, wts, fc_w, fc_b, out);
}